// Round 9
// baseline (275.520 us; speedup 1.0000x reference)
//
#include <hip/hip_runtime.h>

#define DEVFN __device__ __forceinline__

typedef __attribute__((ext_vector_type(4))) float f32x4;
typedef __attribute__((ext_vector_type(8))) short short8;
typedef __attribute__((ext_vector_type(4))) unsigned int uint4v;
typedef __attribute__((ext_vector_type(8))) unsigned short ushort8;

constexpr int CB = 32;
constexpr int CS = 2048;
constexpr int CD = 1024;
constexpr int CU = 1024;
constexpr int CM = CB * CS;   // 65536

DEVFN unsigned f2bf_u(float f) {
    unsigned u = __float_as_uint(f);
    return (u + 0x7FFFu + ((u >> 16) & 1u)) >> 16;   // RNE f32->bf16
}
DEVFN unsigned f2bf_pack(float lo, float hi) {
    return f2bf_u(lo) | (f2bf_u(hi) << 16);
}
DEVFN short8 cvt8(f32x4 a, f32x4 b) {
    uint4v p;
    p[0] = f2bf_pack(a[0], a[1]);
    p[1] = f2bf_pack(a[2], a[3]);
    p[2] = f2bf_pack(b[0], b[1]);
    p[3] = f2bf_pack(b[2], b[3]);
    return __builtin_bit_cast(short8, p);
}
DEVFN float tanh_fast(float x) {
    float e = exp2f(x * 2.885390081777927f);
    return 1.0f - 2.0f * __builtin_amdgcn_rcpf(e + 1.0f);
}

// ---- bias = b1 + b2 + q@W2, two-stage split-D ----
__global__ void k_bias1(const float* __restrict__ q, const float* __restrict__ W2,
                        float* __restrict__ bpart) {
    int dc = blockIdx.x, b = blockIdx.y;   // 8 x 32
    int t = threadIdx.x;                    // 256
    __shared__ float qs[128];
    if (t < 128) qs[t] = q[b * CD + dc * 128 + t];
    __syncthreads();
    float acc0 = 0.f, acc1 = 0.f, acc2 = 0.f, acc3 = 0.f;
    const float* w2 = W2 + (size_t)(dc * 128) * CU + t;
#pragma unroll 4
    for (int d = 0; d < 128; ++d) {
        float qv = qs[d];
        const float* r = w2 + (size_t)d * CU;
        acc0 += qv * r[0];
        acc1 += qv * r[256];
        acc2 += qv * r[512];
        acc3 += qv * r[768];
    }
    float* o = bpart + (size_t)(b * 8 + dc) * CU + t;
    o[0] = acc0; o[256] = acc1; o[512] = acc2; o[768] = acc3;
}

__global__ void k_bias2(const float* __restrict__ bpart, const float* __restrict__ b1,
                        const float* __restrict__ b2, float* __restrict__ bias) {
    int idx = blockIdx.x * 256 + threadIdx.x;   // 32768
    int b = idx >> 10, u = idx & 1023;
    float s = b1[u] + b2[u];
#pragma unroll
    for (int dc = 0; dc < 8; ++dc) s += bpart[(size_t)(b * 8 + dc) * CU + u];
    bias[idx] = s;
}

// ---- pack W1[D][U] f32 -> bf16, MFMA-B fragment-linear tiles ----
// idx = (kt*4+ut)*8192 + ub*512 + l*8 + j ; d = kt*32 + (l>>4)*8 + j ; u = ut*256 + ub*16 + (l&15)
__global__ void k_packW1(const float* __restrict__ W1, unsigned short* __restrict__ W1p) {
    int tid = blockIdx.x * 256 + threadIdx.x;   // 131072 threads, 8 elems each
    int o8  = tid * 8;
    int l   = (o8 >> 3) & 63;
    int ub  = (o8 >> 9) & 15;
    int ut  = (o8 >> 13) & 3;
    int kt  = o8 >> 15;
    int u  = ut * 256 + ub * 16 + (l & 15);
    int d0 = kt * 32 + (l >> 4) * 8;
    ushort8 v;
#pragma unroll
    for (int j = 0; j < 8; ++j)
        v[j] = (unsigned short)f2bf_u(W1[(size_t)(d0 + j) * CU + u]);
    *(ushort8*)(W1p + o8) = v;
}

// ---- fused score GEMM v6: block = 4 waves (256 thr), tile 128r x 256c,
// wave = 128r x 64c (acc[8][4], same proven footprint). 2 blocks/CU ->
// independent barrier domains give cross-block overlap (m114/m97 recipe).
// A: 2 roles/thread, write-at-top reg recycling, optimal LDS swizzle.
// B: global->reg dbuf, distinct per wave. All waits compiler-counted.
__global__ __launch_bounds__(256, 2) void k_score(
    const float* __restrict__ values, const unsigned short* __restrict__ W1p,
    const float* __restrict__ bias, const float* __restrict__ V,
    float* __restrict__ score4) {
    __shared__ __align__(16) char smem[16384];   // A dbuf 2 x 8 KB; red reuses buf0

    const int t = threadIdx.x;
    const int w = t >> 6, l = t & 63;
    const int p = blockIdx.x;                  // 2048 blocks
    const int L = (p & 7) * 256 + (p >> 3);    // bijective XCD-chunk swizzle
    const int xt = L >> 2;                     // m-tile 0..511 (4 siblings share it)
    const int uc = L & 3;                      // u-chunk 0..3
    const int ph = xt & 31;                    // K-phase (same for siblings -> A coincident)
    const int m0 = xt * 128;
    const int bb = m0 >> 11;                   // batch (128 divides S)

    // A stage, role0: row m0 + t/4 (rows 0..63), k-cell (t&3)*8; role1: +64 rows
    const float* aSrc0 = values + (size_t)(m0 + (t >> 2)) * CD + (t & 3) * 8;
    const float* aSrc1 = aSrc0 + (size_t)64 * CD;
    // LDS swizzle: slot(r,h) = ((r&15)^(h<<2)) | (h<<4)  (optimal both sides)
    const int hh = t & 3;
    const int aWr0 = w * 1024 + (((((t >> 2) & 15) ^ (hh << 2)) | (hh << 4)) << 4);
    const int aWr1 = aWr0 + 4096;              // frag w+4 (rows 64..127)
    const int hR = l >> 4;
    const int aRdOff = ((((l & 15) ^ (hR << 2)) | (hR << 4)) << 4);
    // B: wave w covers cols uc*256 + w*64 (4 frags, no duplication)
    const unsigned short* bBase = W1p + (size_t)uc * 8192 + w * 2048 + l * 8;

    f32x4 acc[8][4];
#pragma unroll
    for (int i = 0; i < 8; ++i)
#pragma unroll
        for (int j = 0; j < 4; ++j) acc[i][j] = f32x4{0.f, 0.f, 0.f, 0.f};

    short8 bF0[4], bF1[4];
    f32x4 a0a, a0b, a1a, a1b;

    // prologue: B(0)->bF0 ; A(0)->buf0 ; A(1)->regs (held) ; barrier
    {
        const unsigned short* bs = bBase + (size_t)ph * 32768;
#pragma unroll
        for (int jj = 0; jj < 4; ++jj)
            bF0[jj] = *(const short8*)(bs + jj * 512);
        a0a = __builtin_nontemporal_load((const f32x4*)(aSrc0 + ph * 32));
        a0b = __builtin_nontemporal_load((const f32x4*)(aSrc0 + ph * 32 + 4));
        a1a = __builtin_nontemporal_load((const f32x4*)(aSrc1 + ph * 32));
        a1b = __builtin_nontemporal_load((const f32x4*)(aSrc1 + ph * 32 + 4));
        *(short8*)(smem + aWr0) = cvt8(a0a, a0b);
        *(short8*)(smem + aWr1) = cvt8(a1a, a1b);
        const int kp1 = (ph + 1) & 31;
        a0a = __builtin_nontemporal_load((const f32x4*)(aSrc0 + kp1 * 32));
        a0b = __builtin_nontemporal_load((const f32x4*)(aSrc0 + kp1 * 32 + 4));
        a1a = __builtin_nontemporal_load((const f32x4*)(aSrc1 + kp1 * 32));
        a1b = __builtin_nontemporal_load((const f32x4*)(aSrc1 + kp1 * 32 + 4));
        asm volatile("s_waitcnt lgkmcnt(0)" ::: "memory");
        asm volatile("s_barrier" ::: "memory");
    }

    // step KT: read buf[KT&1]; write held A(KT+1) -> buf[(KT+1)&1]; load A(KT+2), B(KT+1)
#define SCORE_BODY(KT, BF_CUR, BF_NXT, DO_WRB, DO_LDA)                              \
    {                                                                               \
        const char* aB = smem + ((KT) & 1) * 8192;                                  \
        short8 aF[8];                                                               \
        _Pragma("unroll")                                                           \
        for (int i = 0; i < 8; ++i)                                                 \
            aF[i] = *(const short8*)(aB + i * 1024 + aRdOff);                       \
        if (DO_WRB) {                                                               \
            char* wB = smem + (((KT) + 1) & 1) * 8192;                              \
            *(short8*)(wB + aWr0) = cvt8(a0a, a0b);                                 \
            *(short8*)(wB + aWr1) = cvt8(a1a, a1b);                                 \
            const int kp = ((KT) + 1 + ph) & 31;                                    \
            const unsigned short* bs = bBase + (size_t)kp * 32768;                  \
            _Pragma("unroll")                                                       \
            for (int jj = 0; jj < 4; ++jj)                                          \
                BF_NXT[jj] = *(const short8*)(bs + jj * 512);                       \
        }                                                                           \
        if (DO_LDA) {                                                               \
            const int kp = ((KT) + 2 + ph) & 31;                                    \
            a0a = __builtin_nontemporal_load((const f32x4*)(aSrc0 + kp * 32));      \
            a0b = __builtin_nontemporal_load((const f32x4*)(aSrc0 + kp * 32 + 4));  \
            a1a = __builtin_nontemporal_load((const f32x4*)(aSrc1 + kp * 32));      \
            a1b = __builtin_nontemporal_load((const f32x4*)(aSrc1 + kp * 32 + 4));  \
        }                                                                           \
        __builtin_amdgcn_s_setprio(1);                                              \
        _Pragma("unroll")                                                           \
        for (int i = 0; i < 8; ++i)                                                 \
            _Pragma("unroll")                                                       \
            for (int j = 0; j < 4; ++j)                                             \
                acc[i][j] = __builtin_amdgcn_mfma_f32_16x16x32_bf16(                \
                    aF[i], BF_CUR[j], acc[i][j], 0, 0, 0);                          \
        __builtin_amdgcn_s_setprio(0);                                              \
        asm volatile("s_waitcnt lgkmcnt(0)" ::: "memory");                          \
        asm volatile("s_barrier" ::: "memory");                                     \
    }

    for (int kt = 0; kt < 30; kt += 2) {
        SCORE_BODY(kt,     bF0, bF1, 1, 1)
        SCORE_BODY(kt + 1, bF1, bF0, 1, 1)
    }
    SCORE_BODY(30, bF0, bF1, 1, 0)   // write A(31), load B(31); no more A loads
    SCORE_BODY(31, bF1, bF0, 0, 0)
#undef SCORE_BODY

    // epilogue: partial over this wave's 64 cols, all 128 rows
    float part[8][4];
#pragma unroll
    for (int i = 0; i < 8; ++i)
#pragma unroll
        for (int rr = 0; rr < 4; ++rr) part[i][rr] = 0.f;

#pragma unroll
    for (int j = 0; j < 4; ++j) {
        const int col = uc * 256 + w * 64 + j * 16 + (l & 15);
        const float vv = V[col];
        const float bz = bias[bb * CU + col];
#pragma unroll
        for (int i = 0; i < 8; ++i)
#pragma unroll
            for (int rr = 0; rr < 4; ++rr)
                part[i][rr] += vv * tanh_fast(acc[i][j][rr] + bz);
    }

    float* red = (float*)smem;   // [4][128] f32 = 2 KB in buf0 area
#pragma unroll
    for (int i = 0; i < 8; ++i)
#pragma unroll
        for (int rr = 0; rr < 4; ++rr) {
            float v = part[i][rr];
            v += __shfl_xor(v, 1);
            v += __shfl_xor(v, 2);
            v += __shfl_xor(v, 4);
            v += __shfl_xor(v, 8);
            if ((l & 15) == 0)
                red[w * 128 + i * 16 + (l >> 4) * 4 + rr] = v;
        }
    __syncthreads();
    if (t < 128) {
        float sv = red[t] + red[128 + t] + red[256 + t] + red[384 + t];
        score4[(size_t)uc * CM + m0 + t] = sv;
    }
}

// ---- softmax over S per batch; sums the 4 u-chunk slices ----
__global__ void k_softmax(const float* __restrict__ score4, float* __restrict__ wts) {
    int b = blockIdx.x, t = threadIdx.x;   // 1024 threads
    int i0 = b * CS + t, i1 = i0 + 1024;
    float s0 = score4[i0] + score4[CM + i0] + score4[2 * CM + i0] + score4[3 * CM + i0];
    float s1 = score4[i1] + score4[CM + i1] + score4[2 * CM + i1] + score4[3 * CM + i1];
    __shared__ float red[16];
    int wv = t >> 6, ln = t & 63;
    float m = fmaxf(s0, s1);
#pragma unroll
    for (int o = 32; o >= 1; o >>= 1) m = fmaxf(m, __shfl_xor(m, o));
    if (ln == 0) red[wv] = m;
    __syncthreads();
    float M = red[0];
#pragma unroll
    for (int k = 1; k < 16; ++k) M = fmaxf(M, red[k]);
    float e0 = __expf(s0 - M), e1 = __expf(s1 - M);
    float sm = e0 + e1;
#pragma unroll
    for (int o = 32; o >= 1; o >>= 1) sm += __shfl_xor(sm, o);
    __syncthreads();
    if (ln == 0) red[wv] = sm;
    __syncthreads();
    float T = 0.f;
#pragma unroll
    for (int k = 0; k < 16; ++k) T += red[k];
    float inv = 1.0f / T;
    wts[i0] = e0 * inv;
    wts[i1] = e1 * inv;
}

// ---- context ----
__global__ void k_ctx_part(const float* __restrict__ values, const float* __restrict__ wts,
                           float* __restrict__ part) {
    int b = blockIdx.y, sc = blockIdx.x;   // 32 x 32
    int t = threadIdx.x;                    // 256, float4 each -> full D
    const float* vb = values + ((size_t)b * CS + sc * 64) * CD + t * 4;
    const float* wb = wts + b * CS + sc * 64;
    f32x4 a = {0.f, 0.f, 0.f, 0.f};
#pragma unroll 8
    for (int s = 0; s < 64; ++s) {
        float wgt = wb[s];
        f32x4 v = *(const f32x4*)(vb + (size_t)s * CD);
        a += v * wgt;
    }
    *(f32x4*)(part + (size_t)(b * 32 + sc) * CD + t * 4) = a;
}

__global__ void k_ctx_red(const float* __restrict__ part, float* __restrict__ ctx) {
    int idx = blockIdx.x * 256 + threadIdx.x;   // 32768
    int b = idx >> 10, d = idx & 1023;
    float s = 0.f;
#pragma unroll 8
    for (int c = 0; c < 32; ++c) s += part[(size_t)(b * 32 + c) * CD + d];
    ctx[idx] = s;
}

extern "C" void kernel_launch(void* const* d_in, const int* in_sizes, int n_in,
                              void* d_out, int out_size, void* d_ws, size_t ws_size,
                              hipStream_t stream) {
    const float* query  = (const float*)d_in[0];
    const float* values = (const float*)d_in[1];
    const float* W1     = (const float*)d_in[2];
    const float* b1     = (const float*)d_in[3];
    const float* W2     = (const float*)d_in[4];
    const float* b2     = (const float*)d_in[5];
    const float* V      = (const float*)d_in[6];
    // d_in[7] = bV: softmax shift-invariant, score not an output -> unused

    float* out = (float*)d_out;
    float* ctx = out;            // [32][1024]
    float* wts = out + 32768;    // [32][2048]

    char* ws = (char*)d_ws;
    float*          score4 = (float*)ws;                                       // 1 MB
    float*          bias   = (float*)(ws + (1 << 20));                         // 128 KB
    unsigned short* W1p    = (unsigned short*)(ws + (1 << 20) + (1 << 17));    // 2 MB
    float*          part   = (float*)(ws + (1 << 20) + (1 << 17) + (1 << 21)); // 4 MB
    float*          bpart  = part;   // 1 MB, consumed before k_ctx_part

    k_bias1<<<dim3(8, 32), 256, 0, stream>>>(query, W2, bpart);
    k_bias2<<<128, 256, 0, stream>>>(bpart, b1, b2, bias);
    k_packW1<<<512, 256, 0, stream>>>(W1, W1p);
    k_score<<<2048, 256, 0, stream>>>(values, W1p, bias, V, score4);
    k_softmax<<<32, 1024, 0, stream>>>(score4, wts);
    k_ctx_part<<<dim3(32, 32), 256, 0, stream>>>(values, wts, part);
    k_ctx_red<<<128, 256, 0, stream>>>(part, ctx);
}

// Round 10
// 220.453 us; speedup vs baseline: 1.2498x; 1.2498x over previous
//
#include <hip/hip_runtime.h>

#define DEVFN __device__ __forceinline__

typedef __attribute__((ext_vector_type(4))) float f32x4;
typedef __attribute__((ext_vector_type(8))) short short8;
typedef __attribute__((ext_vector_type(4))) unsigned int uint4v;
typedef __attribute__((ext_vector_type(8))) unsigned short ushort8;

constexpr int CB = 32;
constexpr int CS = 2048;
constexpr int CD = 1024;
constexpr int CU = 1024;
constexpr int CM = CB * CS;   // 65536

DEVFN unsigned f2bf_u(float f) {
    unsigned u = __float_as_uint(f);
    return (u + 0x7FFFu + ((u >> 16) & 1u)) >> 16;   // RNE f32->bf16
}
DEVFN unsigned f2bf_pack(float lo, float hi) {
    return f2bf_u(lo) | (f2bf_u(hi) << 16);
}
DEVFN short8 cvt8(f32x4 a, f32x4 b) {
    uint4v p;
    p[0] = f2bf_pack(a[0], a[1]);
    p[1] = f2bf_pack(a[2], a[3]);
    p[2] = f2bf_pack(b[0], b[1]);
    p[3] = f2bf_pack(b[2], b[3]);
    return __builtin_bit_cast(short8, p);
}
DEVFN float tanh_fast(float x) {
    float e = exp2f(x * 2.885390081777927f);
    return 1.0f - 2.0f * __builtin_amdgcn_rcpf(e + 1.0f);
}

// ---- bias = b1 + b2 + q@W2, two-stage split-D ----
__global__ void k_bias1(const float* __restrict__ q, const float* __restrict__ W2,
                        float* __restrict__ bpart) {
    int dc = blockIdx.x, b = blockIdx.y;   // 8 x 32
    int t = threadIdx.x;                    // 256
    __shared__ float qs[128];
    if (t < 128) qs[t] = q[b * CD + dc * 128 + t];
    __syncthreads();
    float acc0 = 0.f, acc1 = 0.f, acc2 = 0.f, acc3 = 0.f;
    const float* w2 = W2 + (size_t)(dc * 128) * CU + t;
#pragma unroll 4
    for (int d = 0; d < 128; ++d) {
        float qv = qs[d];
        const float* r = w2 + (size_t)d * CU;
        acc0 += qv * r[0];
        acc1 += qv * r[256];
        acc2 += qv * r[512];
        acc3 += qv * r[768];
    }
    float* o = bpart + (size_t)(b * 8 + dc) * CU + t;
    o[0] = acc0; o[256] = acc1; o[512] = acc2; o[768] = acc3;
}

__global__ void k_bias2(const float* __restrict__ bpart, const float* __restrict__ b1,
                        const float* __restrict__ b2, float* __restrict__ bias) {
    int idx = blockIdx.x * 256 + threadIdx.x;   // 32768
    int b = idx >> 10, u = idx & 1023;
    float s = b1[u] + b2[u];
#pragma unroll
    for (int dc = 0; dc < 8; ++dc) s += bpart[(size_t)(b * 8 + dc) * CU + u];
    bias[idx] = s;
}

// ---- pack W1[D][U] f32 -> bf16, MFMA-B fragment-linear tiles ----
// idx = (kt*4+ut)*8192 + ub*512 + l*8 + j ; d = kt*32 + (l>>4)*8 + j ; u = ut*256 + ub*16 + (l&15)
__global__ void k_packW1(const float* __restrict__ W1, unsigned short* __restrict__ W1p) {
    int tid = blockIdx.x * 256 + threadIdx.x;   // 131072 threads, 8 elems each
    int o8  = tid * 8;
    int l   = (o8 >> 3) & 63;
    int ub  = (o8 >> 9) & 15;
    int ut  = (o8 >> 13) & 3;
    int kt  = o8 >> 15;
    int u  = ut * 256 + ub * 16 + (l & 15);
    int d0 = kt * 32 + (l >> 4) * 8;
    ushort8 v;
#pragma unroll
    for (int j = 0; j < 8; ++j)
        v[j] = (unsigned short)f2bf_u(W1[(size_t)(d0 + j) * CU + u]);
    *(ushort8*)(W1p + o8) = v;
}

// ---- fused score GEMM v7: BM=128 x U_blk=512, 8 waves, wave 128r x 64c.
// 3-buffer A-LDS pipeline: A global->reg 3 steps ahead, ds_write 2 steps ahead
// of its read -> top-of-step wait is COUNTED lgkmcnt(1), never a drain (m218).
// Single barrier/step. XOR swizzle <=2-way both sides. B global->reg, counted
// vmcnt by compiler. A in L2 (no nt) so uc-siblings share; ph is xt-based.
__global__ __launch_bounds__(512, 2) void k_score(
    const float* __restrict__ values, const unsigned short* __restrict__ W1p,
    const float* __restrict__ bias, const float* __restrict__ V,
    float* __restrict__ score2) {
    __shared__ __align__(16) char smem[24576];   // 3 x 8 KB A bufs; red reuses buf0

    const int t = threadIdx.x;
    const int w = t >> 6, l = t & 63;
    const int p = blockIdx.x;                  // 1024 blocks
    const int xt = (p & 7) + (p >> 4) * 8;     // m-tile 0..511
    const int uc = (p >> 3) & 1;               // uc-sibling pair p, p+8: same XCD
    const int ph = xt & 31;                    // K-phase rotation (same for siblings)
    const int m0 = xt * 128;
    const int bb = m0 >> 11;                   // batch (128 divides S)

    // A reg-stage: thread t covers row m0 + (t>>2), k-cells (t&3)*8 .. +7
    const float* aSrc = values + (size_t)(m0 + (t >> 2)) * CD + (t & 3) * 8;
    // frag-linear bf16 LDS, XOR swizzle ps(ll) = ll ^ (((ll>>4)&3)<<1)  (<=2-way)
    const int llw = (l >> 2) | ((l & 3) << 4);
    const int aWr = w * 1024 + ((llw ^ (((llw >> 4) & 3) << 1)) << 4);
    const int aRd = (l ^ (((l >> 4) & 3) << 1)) << 4;
    // B: wave w covers cols uc*512 + w*64 (4 frags of 1KB, coalesced)
    const unsigned short* bBase = W1p + (size_t)(uc * 2 + (w >> 2)) * 8192
                                + (w & 3) * 2048 + l * 8;

    f32x4 acc[8][4];
#pragma unroll
    for (int i = 0; i < 8; ++i)
#pragma unroll
        for (int j = 0; j < 4; ++j) acc[i][j] = f32x4{0.f, 0.f, 0.f, 0.f};

    short8 bF0[4], bF1[4];
    f32x4 pXa, pXb, pYa, pYb;    // two A-hold pairs (1-step hold each)
    char* ldsR = (char*)smem;            // read buf for step s   = s%3
    char* ldsW = (char*)smem + 16384;    // write buf for step s  = (s+2)%3

    // prologue: B(0)->bF0 ; A(0)->buf0 ; A(1)->buf1 ; A(2)->pY ; drain ; barrier
    {
        const int k0 = ph, k1 = (ph + 1) & 31, k2 = (ph + 2) & 31;
        const unsigned short* bs = bBase + (size_t)k0 * 32768;
#pragma unroll
        for (int jj = 0; jj < 4; ++jj)
            bF0[jj] = *(const short8*)(bs + jj * 512);
        pXa = *(const f32x4*)(aSrc + k0 * 32);
        pXb = *(const f32x4*)(aSrc + k0 * 32 + 4);
        pYa = *(const f32x4*)(aSrc + k1 * 32);
        pYb = *(const f32x4*)(aSrc + k1 * 32 + 4);
        *(short8*)(smem + aWr) = cvt8(pXa, pXb);
        *(short8*)(smem + 8192 + aWr) = cvt8(pYa, pYb);
        pYa = *(const f32x4*)(aSrc + k2 * 32);
        pYb = *(const f32x4*)(aSrc + k2 * 32 + 4);
        asm volatile("s_waitcnt lgkmcnt(0)" ::: "memory");
        asm volatile("s_barrier" ::: "memory");
    }

    // step s: wait lgkmcnt(1) [write(s-2) drained, write(s-1) in flight]; barrier;
    // issue B(s+1), A(s+3); ds_read buf[s%3]; MFMA; cvt+ds_write A(s+2)->buf[(s+2)%3]
#define SCORE_BODY(KT, BFC, BFN, PWa, PWb, PLa, PLb, DO_LDB, DO_LDA, DO_WR)         \
    {                                                                               \
        asm volatile("s_waitcnt lgkmcnt(1)" ::: "memory");                          \
        asm volatile("s_barrier" ::: "memory");                                     \
        if (DO_LDB) {                                                               \
            const int kp = ((KT) + 1 + ph) & 31;                                    \
            const unsigned short* bs = bBase + (size_t)kp * 32768;                  \
            _Pragma("unroll")                                                       \
            for (int jj = 0; jj < 4; ++jj)                                          \
                BFN[jj] = *(const short8*)(bs + jj * 512);                          \
        }                                                                           \
        if (DO_LDA) {                                                               \
            const int kp = ((KT) + 3 + ph) & 31;                                    \
            PLa = *(const f32x4*)(aSrc + kp * 32);                                  \
            PLb = *(const f32x4*)(aSrc + kp * 32 + 4);                              \
        }                                                                           \
        short8 aF[8];                                                               \
        _Pragma("unroll")                                                           \
        for (int i = 0; i < 8; ++i)                                                 \
            aF[i] = *(const short8*)(ldsR + i * 1024 + aRd);                        \
        __builtin_amdgcn_s_setprio(1);                                              \
        _Pragma("unroll")                                                           \
        for (int i = 0; i < 8; ++i)                                                 \
            _Pragma("unroll")                                                       \
            for (int j = 0; j < 4; ++j)                                             \
                acc[i][j] = __builtin_amdgcn_mfma_f32_16x16x32_bf16(                \
                    aF[i], BFC[j], acc[i][j], 0, 0, 0);                             \
        __builtin_amdgcn_s_setprio(0);                                              \
        if (DO_WR)                                                                  \
            *(short8*)(ldsW + aWr) = cvt8(PWa, PWb);                                \
        ldsW = ldsR;                                                                \
        ldsR = (ldsR == (char*)smem + 16384) ? (char*)smem : ldsR + 8192;           \
    }

    for (int kt = 0; kt < 28; kt += 2) {
        SCORE_BODY(kt,     bF0, bF1, pYa, pYb, pXa, pXb, 1, 1, 1)   // wr A(kt+2)=pY, ld A(kt+3)->pX
        SCORE_BODY(kt + 1, bF1, bF0, pXa, pXb, pYa, pYb, 1, 1, 1)   // wr A(kt+3)=pX, ld A(kt+4)->pY
    }
    SCORE_BODY(28, bF0, bF1, pYa, pYb, pXa, pXb, 1, 1, 1)   // wr A(30), ld A(31)->pX
    SCORE_BODY(29, bF1, bF0, pXa, pXb, pYa, pYb, 1, 0, 1)   // wr A(31)=pX
    SCORE_BODY(30, bF0, bF1, pYa, pYb, pXa, pXb, 1, 0, 0)
    SCORE_BODY(31, bF1, bF0, pXa, pXb, pYa, pYb, 0, 0, 0)
#undef SCORE_BODY

    // epilogue: partial over this wave's 64 cols, all 128 rows
    float part[8][4];
#pragma unroll
    for (int i = 0; i < 8; ++i)
#pragma unroll
        for (int rr = 0; rr < 4; ++rr) part[i][rr] = 0.f;

#pragma unroll
    for (int j = 0; j < 4; ++j) {
        const int col = uc * 512 + w * 64 + j * 16 + (l & 15);
        const float vv = V[col];
        const float bz = bias[bb * CU + col];
#pragma unroll
        for (int i = 0; i < 8; ++i)
#pragma unroll
            for (int rr = 0; rr < 4; ++rr)
                part[i][rr] += vv * tanh_fast(acc[i][j][rr] + bz);
    }

    __syncthreads();
    float* red = (float*)smem;   // [8][128] f32 = 4 KB
#pragma unroll
    for (int i = 0; i < 8; ++i)
#pragma unroll
        for (int rr = 0; rr < 4; ++rr) {
            float v = part[i][rr];
            v += __shfl_xor(v, 1);
            v += __shfl_xor(v, 2);
            v += __shfl_xor(v, 4);
            v += __shfl_xor(v, 8);
            if ((l & 15) == 0)
                red[w * 128 + i * 16 + (l >> 4) * 4 + rr] = v;
        }
    __syncthreads();
    if (t < 128) {
        float sv = 0.f;
#pragma unroll
        for (int ww = 0; ww < 8; ++ww) sv += red[ww * 128 + t];
        score2[(size_t)uc * CM + m0 + t] = sv;
    }
}

// ---- softmax over S per batch; sums the 2 u-chunk slices ----
__global__ void k_softmax(const float* __restrict__ score2, float* __restrict__ wts) {
    int b = blockIdx.x, t = threadIdx.x;   // 1024 threads
    int i0 = b * CS + t, i1 = i0 + 1024;
    float s0 = score2[i0] + score2[CM + i0];
    float s1 = score2[i1] + score2[CM + i1];
    __shared__ float red[16];
    int wv = t >> 6, ln = t & 63;
    float m = fmaxf(s0, s1);
#pragma unroll
    for (int o = 32; o >= 1; o >>= 1) m = fmaxf(m, __shfl_xor(m, o));
    if (ln == 0) red[wv] = m;
    __syncthreads();
    float M = red[0];
#pragma unroll
    for (int k = 1; k < 16; ++k) M = fmaxf(M, red[k]);
    float e0 = __expf(s0 - M), e1 = __expf(s1 - M);
    float sm = e0 + e1;
#pragma unroll
    for (int o = 32; o >= 1; o >>= 1) sm += __shfl_xor(sm, o);
    __syncthreads();
    if (ln == 0) red[wv] = sm;
    __syncthreads();
    float T = 0.f;
#pragma unroll
    for (int k = 0; k < 16; ++k) T += red[k];
    float inv = 1.0f / T;
    wts[i0] = e0 * inv;
    wts[i1] = e1 * inv;
}

// ---- context ----
__global__ void k_ctx_part(const float* __restrict__ values, const float* __restrict__ wts,
                           float* __restrict__ part) {
    int b = blockIdx.y, sc = blockIdx.x;   // 32 x 32
    int t = threadIdx.x;                    // 256, float4 each -> full D
    const float* vb = values + ((size_t)b * CS + sc * 64) * CD + t * 4;
    const float* wb = wts + b * CS + sc * 64;
    f32x4 a = {0.f, 0.f, 0.f, 0.f};
#pragma unroll 8
    for (int s = 0; s < 64; ++s) {
        float wgt = wb[s];
        f32x4 v = *(const f32x4*)(vb + (size_t)s * CD);
        a += v * wgt;
    }
    *(f32x4*)(part + (size_t)(b * 32 + sc) * CD + t * 4) = a;
}

__global__ void k_ctx_red(const float* __restrict__ part, float* __restrict__ ctx) {
    int idx = blockIdx.x * 256 + threadIdx.x;   // 32768
    int b = idx >> 10, d = idx & 1023;
    float s = 0.f;
#pragma unroll 8
    for (int c = 0; c < 32; ++c) s += part[(size_t)(b * 32 + c) * CD + d];
    ctx[idx] = s;
}

extern "C" void kernel_launch(void* const* d_in, const int* in_sizes, int n_in,
                              void* d_out, int out_size, void* d_ws, size_t ws_size,
                              hipStream_t stream) {
    const float* query  = (const float*)d_in[0];
    const float* values = (const float*)d_in[1];
    const float* W1     = (const float*)d_in[2];
    const float* b1     = (const float*)d_in[3];
    const float* W2     = (const float*)d_in[4];
    const float* b2     = (const float*)d_in[5];
    const float* V      = (const float*)d_in[6];
    // d_in[7] = bV: softmax shift-invariant, score not an output -> unused

    float* out = (float*)d_out;
    float* ctx = out;            // [32][1024]
    float* wts = out + 32768;    // [32][2048]

    char* ws = (char*)d_ws;
    float*          score2 = (float*)ws;                                       // 512 KB (1 MB reserved)
    float*          bias   = (float*)(ws + (1 << 20));                         // 128 KB
    unsigned short* W1p    = (unsigned short*)(ws + (1 << 20) + (1 << 17));    // 2 MB
    float*          part   = (float*)(ws + (1 << 20) + (1 << 17) + (1 << 21)); // 4 MB
    float*          bpart  = part;   // 1 MB, consumed before k_ctx_part

    k_bias1<<<dim3(8, 32), 256, 0, stream>>>(query, W2, bpart);
    k_bias2<<<128, 256, 0, stream>>>(bpart, b1, b2, bias);
    k_packW1<<<512, 256, 0, stream>>>(W1, W1p);
    k_score<<<1024, 512, 0, stream>>>(values, W1p, bias, V, score2);
    k_softmax<<<32, 1024, 0, stream>>>(score2, wts);
    k_ctx_part<<<dim3(32, 32), 256, 0, stream>>>(values, wts, part);
    k_ctx_red<<<128, 256, 0, stream>>>(part, ctx);
}